// Round 5
// baseline (424.678 us; speedup 1.0000x reference)
//
#include <hip/hip_runtime.h>

#define NA 50000
#define NP 50000
#define NE 800000
#define D 128
#define OUTD 32
#define NSEG 150000
#define DD (D * D)
#define CAP 64

typedef float f32x4 __attribute__((ext_vector_type(4)));
typedef short s16x8 __attribute__((ext_vector_type(8)));

__device__ __forceinline__ ushort f2b(float f) {
    uint x = __float_as_uint(f);
    x += ((x >> 16) & 1u) + 0x7fffu;   // round-to-nearest-even
    return (ushort)(x >> 16);
}

// ---------------- fused front: cvt_x | prep_w | bucket-scatter ----------------
// One dispatch, three block ranges. The scatter part is atomic-latency bound
// (VALU ~1%, HBM ~11%), so the cvt/prep work rides along for free.

#define CVT_BLOCKS 12500   // 3.2M float4 (both feature matrices)
#define PREP_BLOCKS 465
#define SCAT_BLOCKS 9375   // 2.4M edges

__global__ __launch_bounds__(256) void fused_front(
    const float* __restrict__ xa, const float* __restrict__ xp,
    ushort* __restrict__ oa, ushort* __restrict__ op,
    const float* __restrict__ Wl, const float* __restrict__ Wr,
    const float* __restrict__ linW, const float* __restrict__ bl,
    ushort* __restrict__ wt, float* __restrict__ bsum_p,
    const int* __restrict__ sw, const int* __restrict__ dw,
    const int* __restrict__ sc, const int* __restrict__ dc,
    const int* __restrict__ swb, const int* __restrict__ dwb,
    int* __restrict__ cnt, ushort* __restrict__ bucket)
{
    int b = blockIdx.x, t = threadIdx.x;
    if (b < CVT_BLOCKS) {
        // x -> bf16
        int i = b * 256 + t;
        const int per = NA * D / 4;
        const float* src; ushort* dst; int li;
        if (i < per) { src = xa; dst = oa; li = i; }
        else { src = xp; dst = op; li = i - per; }
        float4 v = *(const float4*)&src[(size_t)li * 4];
        ushort4 o;
        o.x = f2b(v.x); o.y = f2b(v.y); o.z = f2b(v.z); o.w = f2b(v.w);
        *(ushort4*)&dst[(size_t)li * 4] = o;
    } else if (b < CVT_BLOCKS + PREP_BLOCKS) {
        // weights -> bf16 transposed: wt[j][n*128+k] = W_j[k][n]
        int b2 = b - CVT_BLOCKS;
        if (b2 < 448) {
            int job = b2 >> 6;
            int idx = (b2 & 63) * 256 + t;
            int n = idx >> 7, k = idx & 127;
            const float* src;
            float add = 0.f;
            switch (job) {
                case 0: src = Wl + 0 * DD; break;
                case 1: src = Wl + 2 * DD; break;
                case 2: src = Wr + 0 * DD; add = Wr[2 * DD + k * D + n]; break;
                case 3: src = Wl + 1 * DD; break;
                case 4: src = Wr + 1 * DD; break;
                case 5: src = Wl + 4 * DD; break;
                default: src = Wr + 4 * DD; break;
            }
            wt[(size_t)job * DD + idx] = f2b(src[k * D + n] + add);
        } else if (b2 < 464) {
            int idx = (b2 - 448) * 256 + t;    // linW^T: n<32, k<128
            int n = idx >> 7, k = idx & 127;
            wt[(size_t)7 * DD + idx] = f2b(linW[k * OUTD + n]);
        } else {
            if (t < D) bsum_p[t] = bl[t] + bl[2 * D + t];
        }
    } else {
        // bucket scatter: one atomic pass does count AND place
        int i = (b - CVT_BLOCKS - PREP_BLOCKS) * 256 + t;
        if (i >= 3 * NE) return;
        int r = (i >= NE) + (i >= 2 * NE);
        int e = i - r * NE;
        const int* sp = (r == 0) ? sw : ((r == 1) ? sc : swb);
        const int* dp = (r == 0) ? dw : ((r == 1) ? dc : dwb);
        int d = dp[e] + r * 50000;
        int slot = atomicAdd(&cnt[d], 1);
        if (slot < CAP) bucket[(size_t)d * CAP + slot] = (ushort)sp[e];
    }
}

// ---------------- gather-mean from buckets (bf16 in/out, f32 accum) ----------------
// wid in [0,150000): seg0 writes(a->p), seg1 cites(p->p), seg2 written_by(p->a)

__global__ __launch_bounds__(256) void gather3(
    const ushort* __restrict__ xa, const ushort* __restrict__ xp,
    const int* __restrict__ cnt, const ushort* __restrict__ bucket,
    ushort* __restrict__ agg3)
{
    int wid = (blockIdx.x * 256 + threadIdx.x) >> 6;
    if (wid >= NSEG) return;
    const ushort* x = (wid < 50000) ? xa : xp;
    int lane = threadIdx.x & 63;
    int deg = __builtin_amdgcn_readfirstlane(cnt[wid]);
    int n = deg > CAP ? CAP : deg;
    const ushort* bk = bucket + (size_t)wid * CAP;
    float ax = 0.f, ay = 0.f, bx = 0.f, by = 0.f;
    int j = 0;
    for (; j + 4 <= n; j += 4) {
        int s0 = bk[j], s1 = bk[j + 1], s2 = bk[j + 2], s3 = bk[j + 3];
        uint u0 = *(const uint*)&x[(size_t)s0 * D + lane * 2];
        uint u1 = *(const uint*)&x[(size_t)s1 * D + lane * 2];
        uint u2 = *(const uint*)&x[(size_t)s2 * D + lane * 2];
        uint u3 = *(const uint*)&x[(size_t)s3 * D + lane * 2];
        ax += __uint_as_float(u0 << 16); ay += __uint_as_float(u0 & 0xffff0000u);
        bx += __uint_as_float(u1 << 16); by += __uint_as_float(u1 & 0xffff0000u);
        ax += __uint_as_float(u2 << 16); ay += __uint_as_float(u2 & 0xffff0000u);
        bx += __uint_as_float(u3 << 16); by += __uint_as_float(u3 & 0xffff0000u);
    }
    for (; j < n; ++j) {
        int s0 = bk[j];
        uint u0 = *(const uint*)&x[(size_t)s0 * D + lane * 2];
        ax += __uint_as_float(u0 << 16); ay += __uint_as_float(u0 & 0xffff0000u);
    }
    float scl = (deg > 0) ? 1.0f / (float)deg : 0.f;
    float rx = (ax + bx) * scl, ry = (ay + by) * scl;
    uint pk = (uint)f2b(rx) | ((uint)f2b(ry) << 16);
    *(uint*)&agg3[(size_t)wid * D + lane * 2] = pk;
}

// single-relation gather (layer 1, written_by buckets)
__global__ __launch_bounds__(256) void gather_l1(
    const ushort* __restrict__ x, const int* __restrict__ cnt,
    const ushort* __restrict__ bucket, ushort* __restrict__ out, int nn)
{
    int wid = (blockIdx.x * 256 + threadIdx.x) >> 6;
    if (wid >= nn) return;
    int lane = threadIdx.x & 63;
    int deg = __builtin_amdgcn_readfirstlane(cnt[wid]);
    int n = deg > CAP ? CAP : deg;
    const ushort* bk = bucket + (size_t)wid * CAP;
    float ax = 0.f, ay = 0.f, bx = 0.f, by = 0.f;
    int j = 0;
    for (; j + 4 <= n; j += 4) {
        int s0 = bk[j], s1 = bk[j + 1], s2 = bk[j + 2], s3 = bk[j + 3];
        uint u0 = *(const uint*)&x[(size_t)s0 * D + lane * 2];
        uint u1 = *(const uint*)&x[(size_t)s1 * D + lane * 2];
        uint u2 = *(const uint*)&x[(size_t)s2 * D + lane * 2];
        uint u3 = *(const uint*)&x[(size_t)s3 * D + lane * 2];
        ax += __uint_as_float(u0 << 16); ay += __uint_as_float(u0 & 0xffff0000u);
        bx += __uint_as_float(u1 << 16); by += __uint_as_float(u1 & 0xffff0000u);
        ax += __uint_as_float(u2 << 16); ay += __uint_as_float(u2 & 0xffff0000u);
        bx += __uint_as_float(u3 << 16); by += __uint_as_float(u3 & 0xffff0000u);
    }
    for (; j < n; ++j) {
        int s0 = bk[j];
        uint u0 = *(const uint*)&x[(size_t)s0 * D + lane * 2];
        ax += __uint_as_float(u0 << 16); ay += __uint_as_float(u0 & 0xffff0000u);
    }
    float scl = (deg > 0) ? 1.0f / (float)deg : 0.f;
    float rx = (ax + bx) * scl, ry = (ay + by) * scl;
    uint pk = (uint)f2b(rx) | ((uint)f2b(ry) << 16);
    *(uint*)&out[(size_t)wid * D + lane * 2] = pk;
}

// ---------------- MFMA bf16 GEMM core ----------------

#define LDA 136

__device__ __forceinline__ void gemm_core(
    ushort* As, f32x4 (&acc)[2][4],
    const ushort* __restrict__ A0, const ushort* __restrict__ WT0,
    const ushort* __restrict__ A1, const ushort* __restrict__ WT1,
    const ushort* __restrict__ A2, const ushort* __restrict__ WT2,
    int nseg, int brow, int M)
{
    const int t = threadIdx.x;
    const int w = t >> 6;
    const int l = t & 63;
    const int wr = w >> 1, wc = w & 1;
    const int l15 = l & 15, l4 = l >> 4;

    for (int s = 0; s < nseg; ++s) {
        const ushort* A = (s == 0) ? A0 : ((s == 1) ? A1 : A2);
        const ushort* WT = (s == 0) ? WT0 : ((s == 1) ? WT1 : WT2);

        if (s) __syncthreads();
#pragma unroll
        for (int it = 0; it < 4; ++it) {
            int f = it * 256 + t;
            int row = f >> 4, cc = f & 15;
            int grow = brow + row;
            float4 v = make_float4(0.f, 0.f, 0.f, 0.f);
            if (grow < M) v = *(const float4*)&A[(size_t)grow * D + cc * 8];
            *(float4*)&As[row * LDA + cc * 8] = v;
        }
        s16x8 Bf[4][4];
#pragma unroll
        for (int ni = 0; ni < 4; ++ni)
#pragma unroll
            for (int ks = 0; ks < 4; ++ks)
                Bf[ni][ks] = *(const s16x8*)&WT[(size_t)(wc * 64 + ni * 16 + l15) * D + ks * 32 + l4 * 8];
        __syncthreads();

#pragma unroll
        for (int ks = 0; ks < 4; ++ks) {
            s16x8 af[2];
#pragma unroll
            for (int mi = 0; mi < 2; ++mi)
                af[mi] = *(const s16x8*)&As[(wr * 32 + mi * 16 + l15) * LDA + ks * 32 + l4 * 8];
#pragma unroll
            for (int mi = 0; mi < 2; ++mi)
#pragma unroll
                for (int ni = 0; ni < 4; ++ni)
                    acc[mi][ni] = __builtin_amdgcn_mfma_f32_16x16x32_bf16(
                        af[mi], Bf[ni][ks], acc[mi][ni], 0, 0, 0);
        }
    }
}

// both layer-0 GEMMs in one dispatch: blocks [0,782) -> papers, [782,1564) -> authors
__global__ __launch_bounds__(256) void gemm_pair(
    const ushort* __restrict__ agg3, const ushort* __restrict__ xb_p,
    const ushort* __restrict__ xb_a, const ushort* __restrict__ wt,
    const float* __restrict__ bsum_p, const float* __restrict__ bl,
    ushort* __restrict__ p1b, ushort* __restrict__ a1b)
{
    __shared__ ushort As[64 * LDA];
    const int t = threadIdx.x;
    const int w = t >> 6;
    const int l = t & 63;
    const int wr = w >> 1, wc = w & 1;
    const int l15 = l & 15, l4 = l >> 4;

    f32x4 acc[2][4];
#pragma unroll
    for (int i = 0; i < 2; ++i)
#pragma unroll
        for (int j = 0; j < 4; ++j) acc[i][j] = (f32x4){0.f, 0.f, 0.f, 0.f};

    bool isP = blockIdx.x < 782;
    int bIdx = isP ? blockIdx.x : blockIdx.x - 782;
    int brow = bIdx * 64;
    const float* bias;
    ushort* C;
    if (isP) {
        gemm_core(As, acc, agg3, wt + 0 * DD, agg3 + (size_t)50000 * D, wt + 1 * DD,
                  xb_p, wt + 2 * DD, 3, brow, NP);
        bias = bsum_p; C = p1b;
    } else {
        gemm_core(As, acc, agg3 + (size_t)100000 * D, wt + 3 * DD, xb_a, wt + 4 * DD,
                  nullptr, nullptr, 2, brow, NA);
        bias = bl + 1 * D; C = a1b;
    }

#pragma unroll
    for (int mi = 0; mi < 2; ++mi) {
#pragma unroll
        for (int ni = 0; ni < 4; ++ni) {
            int col = wc * 64 + ni * 16 + l15;
            float bb = bias[col];
#pragma unroll
            for (int r = 0; r < 4; ++r) {
                int grow = brow + wr * 32 + mi * 16 + l4 * 4 + r;
                if (grow >= 50000) continue;
                float v = acc[mi][ni][r] + bb;
                v = v > 0.f ? v : 0.01f * v;
                C[(size_t)grow * D + col] = f2b(v);
            }
        }
    }
}

// layer-1 author GEMM with fused final projection: out = lrelu(...)@linW + linb
__global__ __launch_bounds__(256) void gemm_final(
    const ushort* __restrict__ A0, const ushort* __restrict__ WT0,
    const ushort* __restrict__ A1, const ushort* __restrict__ WT1,
    const float* __restrict__ bias,
    const ushort* __restrict__ linWT, const float* __restrict__ linb,
    float* __restrict__ fout, int M)
{
    __shared__ ushort As[64 * LDA];
    const int t = threadIdx.x;
    const int w = t >> 6;
    const int l = t & 63;
    const int wr = w >> 1, wc = w & 1;
    const int l15 = l & 15, l4 = l >> 4;
    const int brow = blockIdx.x * 64;

    f32x4 acc[2][4];
#pragma unroll
    for (int i = 0; i < 2; ++i)
#pragma unroll
        for (int j = 0; j < 4; ++j) acc[i][j] = (f32x4){0.f, 0.f, 0.f, 0.f};

    gemm_core(As, acc, A0, WT0, A1, WT1, nullptr, nullptr, 2, brow, M);

    __syncthreads();
#pragma unroll
    for (int mi = 0; mi < 2; ++mi) {
#pragma unroll
        for (int ni = 0; ni < 4; ++ni) {
            int col = wc * 64 + ni * 16 + l15;
            float bb = bias[col];
#pragma unroll
            for (int r = 0; r < 4; ++r) {
                int row = wr * 32 + mi * 16 + l4 * 4 + r;
                float v = acc[mi][ni][r] + bb;
                v = v > 0.f ? v : 0.01f * v;
                As[row * LDA + col] = f2b(v);
            }
        }
    }
    __syncthreads();
    f32x4 a2c[2];
    a2c[0] = (f32x4){0.f, 0.f, 0.f, 0.f};
    a2c[1] = (f32x4){0.f, 0.f, 0.f, 0.f};
#pragma unroll
    for (int ks = 0; ks < 4; ++ks) {
        s16x8 af = *(const s16x8*)&As[(w * 16 + l15) * LDA + ks * 32 + l4 * 8];
#pragma unroll
        for (int ni = 0; ni < 2; ++ni) {
            s16x8 bf = *(const s16x8*)&linWT[(size_t)(ni * 16 + l15) * D + ks * 32 + l4 * 8];
            a2c[ni] = __builtin_amdgcn_mfma_f32_16x16x32_bf16(af, bf, a2c[ni], 0, 0, 0);
        }
    }
#pragma unroll
    for (int ni = 0; ni < 2; ++ni) {
        int col = ni * 16 + l15;
        float bb = linb[col];
#pragma unroll
        for (int r = 0; r < 4; ++r) {
            int grow = brow + w * 16 + l4 * 4 + r;
            if (grow < M) fout[(size_t)grow * OUTD + col] = a2c[ni][r] + bb;
        }
    }
}

// ---------------- launch ----------------

extern "C" void kernel_launch(void* const* d_in, const int* in_sizes, int n_in,
                              void* d_out, int out_size, void* d_ws, size_t ws_size,
                              hipStream_t stream)
{
    const float* x_author = (const float*)d_in[0];
    const float* x_paper  = (const float*)d_in[1];
    const int*   e_w      = (const int*)d_in[2];   // author -> paper
    const int*   e_wb     = (const int*)d_in[3];   // paper  -> author
    const int*   e_c      = (const int*)d_in[4];   // paper  -> paper
    const float* Wl       = (const float*)d_in[5];
    const float* bl       = (const float*)d_in[6];
    const float* Wr       = (const float*)d_in[7];
    const float* linW     = (const float*)d_in[8];
    const float* linb     = (const float*)d_in[9];
    float* out = (float*)d_out;

    // ---- workspace ----
    int* ib = (int*)d_ws;
    int* cnt = ib;                                   // 150016 ints
    ushort* bucket = (ushort*)(ib + 150016);         // 9.6M ushorts (19.2MB)
    float* bsum_p = (float*)(ib + 150016 + 4800000); // 128 floats
    ushort* ub = (ushort*)(ib + 150016 + 4800000 + 128);
    ushort* wt   = ub;                               // 8*16384
    ushort* xb_a = ub + 131072;
    ushort* xb_p = xb_a + (size_t)NA * D;
    ushort* agg3 = xb_p + (size_t)NP * D;            // [150000][D]
    ushort* p1b  = agg3 + (size_t)NSEG * D;
    ushort* a1b  = p1b + (size_t)NP * D;
    ushort* g2b  = agg3;   // reuse: aggw consumed by gemm_pair before gather_l1

    hipMemsetAsync(cnt, 0, 150016 * sizeof(int), stream);

    // cvt_x | prep_w | bucket-scatter, one dispatch
    fused_front<<<CVT_BLOCKS + PREP_BLOCKS + SCAT_BLOCKS, 256, 0, stream>>>(
        x_author, x_paper, xb_a, xb_p,
        Wl, Wr, linW, bl, wt, bsum_p,
        e_w, e_w + NE, e_c, e_c + NE, e_wb, e_wb + NE,
        cnt, bucket);

    // layer-0 gathers (150000 waves)
    gather3<<<NSEG * 64 / 256, 256, 0, stream>>>(xb_a, xb_p, cnt, bucket, agg3);

    // both layer-0 GEMMs
    gemm_pair<<<1564, 256, 0, stream>>>(agg3, xb_p, xb_a, wt, bsum_p, bl, p1b, a1b);

    // layer-1 gather of p1 over written_by buckets
    gather_l1<<<NA * 64 / 256, 256, 0, stream>>>(
        p1b, cnt + 100000, bucket + (size_t)100000 * CAP, g2b, NA);

    // a2 = lrelu(g2@Wl11 + a1@Wr11 + bl11); out = a2@linW + linb (fused)
    gemm_final<<<(NA + 63) / 64, 256, 0, stream>>>(
        g2b, wt + 5 * DD, a1b, wt + 6 * DD, bl + 4 * D, wt + 7 * DD, linb, out, NA);
}

// Round 6
// 273.967 us; speedup vs baseline: 1.5501x; 1.5501x over previous
//
#include <hip/hip_runtime.h>

#define NA 50000
#define NP 50000
#define NE 800000
#define D 128
#define OUTD 32
#define NSEG 150000
#define DD (D * D)
#define NCH 196        // chunks per relation (4096 edges each)
#define NBK 588        // 3 relations x 196 buckets (dst>>8)
#define CHE 4096       // edges per chunk

typedef float f32x4 __attribute__((ext_vector_type(4)));
typedef short s16x8 __attribute__((ext_vector_type(8)));

__device__ __forceinline__ ushort f2b(float f) {
    uint x = __float_as_uint(f);
    x += ((x >> 16) & 1u) + 0x7fffu;   // round-to-nearest-even
    return (ushort)(x >> 16);
}

// ---------------- P1: cvt_x | prep_w | per-chunk histograms of dst>>8 ----------------

#define CVT_BLOCKS 12500   // 3.2M float4
#define PREP_BLOCKS 465
#define HIST_BLOCKS NBK

__global__ __launch_bounds__(256) void front(
    const float* __restrict__ xa, const float* __restrict__ xp,
    ushort* __restrict__ oa, ushort* __restrict__ op,
    const float* __restrict__ Wl, const float* __restrict__ Wr,
    const float* __restrict__ linW, const float* __restrict__ bl,
    ushort* __restrict__ wt, float* __restrict__ bsum_p,
    const int* __restrict__ dw, const int* __restrict__ dc, const int* __restrict__ dwb,
    int* __restrict__ Hglob)
{
    __shared__ int hist[NCH];
    int b = blockIdx.x, t = threadIdx.x;
    if (b < CVT_BLOCKS) {
        int i = b * 256 + t;
        const int per = NA * D / 4;
        const float* src; ushort* dst; int li;
        if (i < per) { src = xa; dst = oa; li = i; }
        else { src = xp; dst = op; li = i - per; }
        float4 v = *(const float4*)&src[(size_t)li * 4];
        ushort4 o;
        o.x = f2b(v.x); o.y = f2b(v.y); o.z = f2b(v.z); o.w = f2b(v.w);
        *(ushort4*)&dst[(size_t)li * 4] = o;
    } else if (b < CVT_BLOCKS + PREP_BLOCKS) {
        int b2 = b - CVT_BLOCKS;
        if (b2 < 448) {
            int job = b2 >> 6;
            int idx = (b2 & 63) * 256 + t;
            int n = idx >> 7, k = idx & 127;
            const float* src;
            float add = 0.f;
            switch (job) {
                case 0: src = Wl + 0 * DD; break;
                case 1: src = Wl + 2 * DD; break;
                case 2: src = Wr + 0 * DD; add = Wr[2 * DD + k * D + n]; break;
                case 3: src = Wl + 1 * DD; break;
                case 4: src = Wr + 1 * DD; break;
                case 5: src = Wl + 4 * DD; break;
                default: src = Wr + 4 * DD; break;
            }
            wt[(size_t)job * DD + idx] = f2b(src[k * D + n] + add);
        } else if (b2 < 464) {
            int idx = (b2 - 448) * 256 + t;    // linW^T: n<32, k<128
            int n = idx >> 7, k = idx & 127;
            wt[(size_t)7 * DD + idx] = f2b(linW[k * OUTD + n]);
        } else {
            if (t < D) bsum_p[t] = bl[t] + bl[2 * D + t];
        }
    } else {
        int hb = b - CVT_BLOCKS - PREP_BLOCKS;
        int r = hb / NCH, c = hb % NCH;
        const int* dp = (r == 0) ? dw : ((r == 1) ? dc : dwb);
        for (int i = t; i < NCH; i += 256) hist[i] = 0;
        __syncthreads();
        int base = c * CHE;
#pragma unroll
        for (int i = 0; i < 16; ++i) {
            int e = base + i * 256 + t;
            if (e < NE) atomicAdd(&hist[dp[e] >> 8], 1);
        }
        __syncthreads();
        for (int dg = t; dg < NCH; dg += 256)
            Hglob[(r * NCH + dg) * NCH + c] = hist[dg];
    }
}

// ---------------- P2a: per-bucket exclusive scan over chunks ----------------

__global__ __launch_bounds__(64) void scan_chunks(
    const int* __restrict__ Hglob, int* __restrict__ OFF, int* __restrict__ T)
{
    int gd = blockIdx.x, t = threadIdx.x;
    int carry = 0;
#pragma unroll
    for (int rnd = 0; rnd < 4; ++rnd) {
        int idx = rnd * 64 + t;
        int v = (idx < NCH) ? Hglob[gd * NCH + idx] : 0;
        int x = v;
#pragma unroll
        for (int off = 1; off < 64; off <<= 1) {
            int y = __shfl_up(x, off, 64);
            if (t >= off) x += y;
        }
        if (idx < NCH) OFF[gd * NCH + idx] = carry + x - v;
        carry += __shfl(x, 63, 64);
    }
    if (t == 0) T[gd] = carry;
}

// ---------------- P2b: exclusive scan over 588 bucket totals ----------------

__global__ __launch_bounds__(64) void scan_buckets(
    const int* __restrict__ T, int* __restrict__ B)
{
    int t = threadIdx.x, carry = 0;
#pragma unroll
    for (int rnd = 0; rnd < 10; ++rnd) {
        int idx = rnd * 64 + t;
        int v = (idx < NBK) ? T[idx] : 0;
        int x = v;
#pragma unroll
        for (int off = 1; off < 64; off <<= 1) {
            int y = __shfl_up(x, off, 64);
            if (t >= off) x += y;
        }
        if (idx < NBK) B[idx] = carry + x - v;
        carry += __shfl(x, 63, 64);
    }
}

// ---------------- P3: scatter edges into buckets (LDS ranks, no global atomics) ----------------

__global__ __launch_bounds__(256) void bucket_scatter(
    const int* __restrict__ sw, const int* __restrict__ dw,
    const int* __restrict__ sc_, const int* __restrict__ dc,
    const int* __restrict__ swb, const int* __restrict__ dwb,
    const int* __restrict__ B, const int* __restrict__ OFF,
    uint* __restrict__ bucketed)
{
    __shared__ int lbase[NCH];
    __shared__ int cnt2[NCH];
    int b = blockIdx.x, t = threadIdx.x;
    int r = b / NCH, c = b % NCH;
    const int* sp = (r == 0) ? sw : ((r == 1) ? sc_ : swb);
    const int* dp = (r == 0) ? dw : ((r == 1) ? dc : dwb);
    for (int i = t; i < NCH; i += 256) {
        int gd = r * NCH + i;
        lbase[i] = B[gd] + OFF[gd * NCH + c];
        cnt2[i] = 0;
    }
    __syncthreads();
    int base = c * CHE;
#pragma unroll
    for (int i = 0; i < 16; ++i) {
        int e = base + i * 256 + t;
        if (e < NE) {
            int d = dp[e], s = sp[e];
            int dg = d >> 8;
            int rk = atomicAdd(&cnt2[dg], 1);
            bucketed[lbase[dg] + rk] = ((uint)d << 16) | (uint)s;
        }
    }
}

// ---------------- P4: within-bucket sort by dst low byte -> csr16 + rowptr ----------------

__global__ __launch_bounds__(256) void bucket_sort(
    const uint* __restrict__ bucketed, const int* __restrict__ B,
    const int* __restrict__ T, ushort* __restrict__ csr16,
    int* __restrict__ rowptr)
{
    __shared__ int h[256], bb[256], c3[256];
    int gd = blockIdx.x, t = threadIdx.x;
    int r = gd / NCH, hb = gd % NCH;
    int beg = B[gd], n = T[gd];
    h[t] = 0; c3[t] = 0;
    __syncthreads();
    for (int i = t; i < n; i += 256)
        atomicAdd(&h[(bucketed[beg + i] >> 16) & 255], 1);
    __syncthreads();
    if (t < 64) {
        int carry = 0;
#pragma unroll
        for (int rnd = 0; rnd < 4; ++rnd) {
            int idx = rnd * 64 + t;
            int v = h[idx], x = v;
#pragma unroll
            for (int off = 1; off < 64; off <<= 1) {
                int y = __shfl_up(x, off, 64);
                if (t >= off) x += y;
            }
            bb[idx] = carry + x - v;
            carry += __shfl(x, 63, 64);
        }
    }
    __syncthreads();
    {
        int dst = hb * 256 + t;
        if (dst < 50000) rowptr[r * 50000 + dst] = beg + bb[t];
    }
    for (int i = t; i < n; i += 256) {
        uint rec = bucketed[beg + i];
        int low = (rec >> 16) & 255;
        int rk = atomicAdd(&c3[low], 1);
        csr16[beg + bb[low] + rk] = (ushort)(rec & 0xffffu);
    }
    if (gd == NBK - 1 && t == 0) rowptr[NSEG] = 3 * NE;
}

// ---------------- gather-mean (bf16 in/out, f32 accum), rowptr + csr16 ----------------

__global__ __launch_bounds__(256) void gather3(
    const ushort* __restrict__ xa, const ushort* __restrict__ xp,
    const int* __restrict__ rowptr, const ushort* __restrict__ csr16,
    ushort* __restrict__ agg3)
{
    int wid = (blockIdx.x * 256 + threadIdx.x) >> 6;
    if (wid >= NSEG) return;
    const ushort* x = (wid < 50000) ? xa : xp;
    int lane = threadIdx.x & 63;
    int beg = __builtin_amdgcn_readfirstlane(rowptr[wid]);
    int end = __builtin_amdgcn_readfirstlane(rowptr[wid + 1]);
    int n = end - beg;
    const ushort* bk = csr16 + beg;
    float ax = 0.f, ay = 0.f, bx = 0.f, by = 0.f;
    int j = 0;
    for (; j + 4 <= n; j += 4) {
        int s0 = bk[j], s1 = bk[j + 1], s2 = bk[j + 2], s3 = bk[j + 3];
        uint u0 = *(const uint*)&x[(size_t)s0 * D + lane * 2];
        uint u1 = *(const uint*)&x[(size_t)s1 * D + lane * 2];
        uint u2 = *(const uint*)&x[(size_t)s2 * D + lane * 2];
        uint u3 = *(const uint*)&x[(size_t)s3 * D + lane * 2];
        ax += __uint_as_float(u0 << 16); ay += __uint_as_float(u0 & 0xffff0000u);
        bx += __uint_as_float(u1 << 16); by += __uint_as_float(u1 & 0xffff0000u);
        ax += __uint_as_float(u2 << 16); ay += __uint_as_float(u2 & 0xffff0000u);
        bx += __uint_as_float(u3 << 16); by += __uint_as_float(u3 & 0xffff0000u);
    }
    for (; j < n; ++j) {
        int s0 = bk[j];
        uint u0 = *(const uint*)&x[(size_t)s0 * D + lane * 2];
        ax += __uint_as_float(u0 << 16); ay += __uint_as_float(u0 & 0xffff0000u);
    }
    float scl = (n > 0) ? 1.0f / (float)n : 0.f;
    float rx = (ax + bx) * scl, ry = (ay + by) * scl;
    uint pk = (uint)f2b(rx) | ((uint)f2b(ry) << 16);
    *(uint*)&agg3[(size_t)wid * D + lane * 2] = pk;
}

__global__ __launch_bounds__(256) void gather_l1(
    const ushort* __restrict__ x, const int* __restrict__ rowptr,
    const ushort* __restrict__ csr16, ushort* __restrict__ out)
{
    int wid = (blockIdx.x * 256 + threadIdx.x) >> 6;
    if (wid >= NA) return;
    int lane = threadIdx.x & 63;
    int beg = __builtin_amdgcn_readfirstlane(rowptr[100000 + wid]);
    int end = __builtin_amdgcn_readfirstlane(rowptr[100000 + wid + 1]);
    int n = end - beg;
    const ushort* bk = csr16 + beg;
    float ax = 0.f, ay = 0.f, bx = 0.f, by = 0.f;
    int j = 0;
    for (; j + 4 <= n; j += 4) {
        int s0 = bk[j], s1 = bk[j + 1], s2 = bk[j + 2], s3 = bk[j + 3];
        uint u0 = *(const uint*)&x[(size_t)s0 * D + lane * 2];
        uint u1 = *(const uint*)&x[(size_t)s1 * D + lane * 2];
        uint u2 = *(const uint*)&x[(size_t)s2 * D + lane * 2];
        uint u3 = *(const uint*)&x[(size_t)s3 * D + lane * 2];
        ax += __uint_as_float(u0 << 16); ay += __uint_as_float(u0 & 0xffff0000u);
        bx += __uint_as_float(u1 << 16); by += __uint_as_float(u1 & 0xffff0000u);
        ax += __uint_as_float(u2 << 16); ay += __uint_as_float(u2 & 0xffff0000u);
        bx += __uint_as_float(u3 << 16); by += __uint_as_float(u3 & 0xffff0000u);
    }
    for (; j < n; ++j) {
        int s0 = bk[j];
        uint u0 = *(const uint*)&x[(size_t)s0 * D + lane * 2];
        ax += __uint_as_float(u0 << 16); ay += __uint_as_float(u0 & 0xffff0000u);
    }
    float scl = (n > 0) ? 1.0f / (float)n : 0.f;
    float rx = (ax + bx) * scl, ry = (ay + by) * scl;
    uint pk = (uint)f2b(rx) | ((uint)f2b(ry) << 16);
    *(uint*)&out[(size_t)wid * D + lane * 2] = pk;
}

// ---------------- MFMA bf16 GEMM core ----------------

#define LDA 136

__device__ __forceinline__ void gemm_core(
    ushort* As, f32x4 (&acc)[2][4],
    const ushort* __restrict__ A0, const ushort* __restrict__ WT0,
    const ushort* __restrict__ A1, const ushort* __restrict__ WT1,
    const ushort* __restrict__ A2, const ushort* __restrict__ WT2,
    int nseg, int brow, int M)
{
    const int t = threadIdx.x;
    const int w = t >> 6;
    const int l = t & 63;
    const int wr = w >> 1, wc = w & 1;
    const int l15 = l & 15, l4 = l >> 4;

    for (int s = 0; s < nseg; ++s) {
        const ushort* A = (s == 0) ? A0 : ((s == 1) ? A1 : A2);
        const ushort* WT = (s == 0) ? WT0 : ((s == 1) ? WT1 : WT2);

        if (s) __syncthreads();
#pragma unroll
        for (int it = 0; it < 4; ++it) {
            int f = it * 256 + t;
            int row = f >> 4, cc = f & 15;
            int grow = brow + row;
            float4 v = make_float4(0.f, 0.f, 0.f, 0.f);
            if (grow < M) v = *(const float4*)&A[(size_t)grow * D + cc * 8];
            *(float4*)&As[row * LDA + cc * 8] = v;
        }
        s16x8 Bf[4][4];
#pragma unroll
        for (int ni = 0; ni < 4; ++ni)
#pragma unroll
            for (int ks = 0; ks < 4; ++ks)
                Bf[ni][ks] = *(const s16x8*)&WT[(size_t)(wc * 64 + ni * 16 + l15) * D + ks * 32 + l4 * 8];
        __syncthreads();

#pragma unroll
        for (int ks = 0; ks < 4; ++ks) {
            s16x8 af[2];
#pragma unroll
            for (int mi = 0; mi < 2; ++mi)
                af[mi] = *(const s16x8*)&As[(wr * 32 + mi * 16 + l15) * LDA + ks * 32 + l4 * 8];
#pragma unroll
            for (int mi = 0; mi < 2; ++mi)
#pragma unroll
                for (int ni = 0; ni < 4; ++ni)
                    acc[mi][ni] = __builtin_amdgcn_mfma_f32_16x16x32_bf16(
                        af[mi], Bf[ni][ks], acc[mi][ni], 0, 0, 0);
        }
    }
}

// both layer-0 GEMMs in one dispatch
__global__ __launch_bounds__(256) void gemm_pair(
    const ushort* __restrict__ agg3, const ushort* __restrict__ xb_p,
    const ushort* __restrict__ xb_a, const ushort* __restrict__ wt,
    const float* __restrict__ bsum_p, const float* __restrict__ bl,
    ushort* __restrict__ p1b, ushort* __restrict__ a1b)
{
    __shared__ ushort As[64 * LDA];
    const int t = threadIdx.x;
    const int w = t >> 6;
    const int l = t & 63;
    const int wr = w >> 1, wc = w & 1;
    const int l15 = l & 15, l4 = l >> 4;

    f32x4 acc[2][4];
#pragma unroll
    for (int i = 0; i < 2; ++i)
#pragma unroll
        for (int j = 0; j < 4; ++j) acc[i][j] = (f32x4){0.f, 0.f, 0.f, 0.f};

    bool isP = blockIdx.x < 782;
    int bIdx = isP ? blockIdx.x : blockIdx.x - 782;
    int brow = bIdx * 64;
    const float* bias;
    ushort* C;
    if (isP) {
        gemm_core(As, acc, agg3, wt + 0 * DD, agg3 + (size_t)50000 * D, wt + 1 * DD,
                  xb_p, wt + 2 * DD, 3, brow, NP);
        bias = bsum_p; C = p1b;
    } else {
        gemm_core(As, acc, agg3 + (size_t)100000 * D, wt + 3 * DD, xb_a, wt + 4 * DD,
                  nullptr, nullptr, 2, brow, NA);
        bias = bl + 1 * D; C = a1b;
    }

#pragma unroll
    for (int mi = 0; mi < 2; ++mi) {
#pragma unroll
        for (int ni = 0; ni < 4; ++ni) {
            int col = wc * 64 + ni * 16 + l15;
            float bb = bias[col];
#pragma unroll
            for (int r = 0; r < 4; ++r) {
                int grow = brow + wr * 32 + mi * 16 + l4 * 4 + r;
                if (grow >= 50000) continue;
                float v = acc[mi][ni][r] + bb;
                v = v > 0.f ? v : 0.01f * v;
                C[(size_t)grow * D + col] = f2b(v);
            }
        }
    }
}

// layer-1 author GEMM with fused final projection
__global__ __launch_bounds__(256) void gemm_final(
    const ushort* __restrict__ A0, const ushort* __restrict__ WT0,
    const ushort* __restrict__ A1, const ushort* __restrict__ WT1,
    const float* __restrict__ bias,
    const ushort* __restrict__ linWT, const float* __restrict__ linb,
    float* __restrict__ fout, int M)
{
    __shared__ ushort As[64 * LDA];
    const int t = threadIdx.x;
    const int w = t >> 6;
    const int l = t & 63;
    const int wr = w >> 1, wc = w & 1;
    const int l15 = l & 15, l4 = l >> 4;
    const int brow = blockIdx.x * 64;

    f32x4 acc[2][4];
#pragma unroll
    for (int i = 0; i < 2; ++i)
#pragma unroll
        for (int j = 0; j < 4; ++j) acc[i][j] = (f32x4){0.f, 0.f, 0.f, 0.f};

    gemm_core(As, acc, A0, WT0, A1, WT1, nullptr, nullptr, 2, brow, M);

    __syncthreads();
#pragma unroll
    for (int mi = 0; mi < 2; ++mi) {
#pragma unroll
        for (int ni = 0; ni < 4; ++ni) {
            int col = wc * 64 + ni * 16 + l15;
            float bb = bias[col];
#pragma unroll
            for (int r = 0; r < 4; ++r) {
                int row = wr * 32 + mi * 16 + l4 * 4 + r;
                float v = acc[mi][ni][r] + bb;
                v = v > 0.f ? v : 0.01f * v;
                As[row * LDA + col] = f2b(v);
            }
        }
    }
    __syncthreads();
    f32x4 a2c[2];
    a2c[0] = (f32x4){0.f, 0.f, 0.f, 0.f};
    a2c[1] = (f32x4){0.f, 0.f, 0.f, 0.f};
#pragma unroll
    for (int ks = 0; ks < 4; ++ks) {
        s16x8 af = *(const s16x8*)&As[(w * 16 + l15) * LDA + ks * 32 + l4 * 8];
#pragma unroll
        for (int ni = 0; ni < 2; ++ni) {
            s16x8 bf = *(const s16x8*)&linWT[(size_t)(ni * 16 + l15) * D + ks * 32 + l4 * 8];
            a2c[ni] = __builtin_amdgcn_mfma_f32_16x16x32_bf16(af, bf, a2c[ni], 0, 0, 0);
        }
    }
#pragma unroll
    for (int ni = 0; ni < 2; ++ni) {
        int col = ni * 16 + l15;
        float bb = linb[col];
#pragma unroll
        for (int r = 0; r < 4; ++r) {
            int grow = brow + w * 16 + l4 * 4 + r;
            if (grow < M) fout[(size_t)grow * OUTD + col] = a2c[ni][r] + bb;
        }
    }
}

// ---------------- launch ----------------

extern "C" void kernel_launch(void* const* d_in, const int* in_sizes, int n_in,
                              void* d_out, int out_size, void* d_ws, size_t ws_size,
                              hipStream_t stream)
{
    const float* x_author = (const float*)d_in[0];
    const float* x_paper  = (const float*)d_in[1];
    const int*   e_w      = (const int*)d_in[2];   // author -> paper  (r=0)
    const int*   e_wb     = (const int*)d_in[3];   // paper  -> author (r=2)
    const int*   e_c      = (const int*)d_in[4];   // paper  -> paper  (r=1)
    const float* Wl       = (const float*)d_in[5];
    const float* bl       = (const float*)d_in[6];
    const float* Wr       = (const float*)d_in[7];
    const float* linW     = (const float*)d_in[8];
    const float* linb     = (const float*)d_in[9];
    float* out = (float*)d_out;

    // ---- workspace ----
    int* ib = (int*)d_ws;
    int* Hglob  = ib;                       // 588*196 = 115248
    int* OFF    = ib + 115248;              // 115248
    int* T      = ib + 230496;              // 588
    int* B      = ib + 231084;              // 589 (pad region to 231680)
    int* rowptr = ib + 231680;              // 150001 (pad to 381696)
    uint* bucketed = (uint*)(ib + 381696);  // 2400000
    ushort* csr16  = (ushort*)(ib + 2781696); // 2400000 ushort (1.2M ints)
    float* bsum_p  = (float*)(ib + 3981696);  // 128
    ushort* ub = (ushort*)(ib + 3981824);
    ushort* wt   = ub;                      // 8*16384
    ushort* xb_a = ub + 131072;
    ushort* xb_p = xb_a + (size_t)NA * D;
    ushort* agg3 = xb_p + (size_t)NP * D;   // [150000][D]
    ushort* p1b  = agg3 + (size_t)NSEG * D;
    ushort* a1b  = p1b + (size_t)NP * D;
    ushort* g2b  = agg3;   // reuse after gemm_pair consumed agg3

    // P1: cvt | prep | histograms (no global atomics anywhere)
    front<<<CVT_BLOCKS + PREP_BLOCKS + HIST_BLOCKS, 256, 0, stream>>>(
        x_author, x_paper, xb_a, xb_p,
        Wl, Wr, linW, bl, wt, bsum_p,
        e_w + NE, e_c + NE, e_wb + NE, Hglob);

    // P2: scans
    scan_chunks<<<NBK, 64, 0, stream>>>(Hglob, OFF, T);
    scan_buckets<<<1, 64, 0, stream>>>(T, B);

    // P3: scatter into buckets
    bucket_scatter<<<NBK, 256, 0, stream>>>(
        e_w, e_w + NE, e_c, e_c + NE, e_wb, e_wb + NE, B, OFF, bucketed);

    // P4: within-bucket sort -> csr16 + rowptr
    bucket_sort<<<NBK, 256, 0, stream>>>(bucketed, B, T, csr16, rowptr);

    // layer-0 gathers (150000 waves)
    gather3<<<NSEG * 64 / 256, 256, 0, stream>>>(xb_a, xb_p, rowptr, csr16, agg3);

    // both layer-0 GEMMs
    gemm_pair<<<1564, 256, 0, stream>>>(agg3, xb_p, xb_a, wt, bsum_p, bl, p1b, a1b);

    // layer-1 gather of p1 over written_by
    gather_l1<<<NA * 64 / 256, 256, 0, stream>>>(p1b, rowptr, csr16, g2b);

    // a2 = lrelu(g2@Wl11 + a1@Wr11 + bl11); out = a2@linW + linb (fused)
    gemm_final<<<(NA + 63) / 64, 256, 0, stream>>>(
        g2b, wt + 5 * DD, a1b, wt + 6 * DD, bl + 4 * D, wt + 7 * DD, linb, out, NA);
}

// Round 7
// 248.512 us; speedup vs baseline: 1.7089x; 1.1024x over previous
//
#include <hip/hip_runtime.h>

#define NA 50000
#define NP 50000
#define NE 800000
#define D 128
#define OUTD 32
#define NSEG 150000
#define DD (D * D)
#define NCH 196        // chunks per relation (4096 edges each)
#define NBK 588        // 3 relations x 196 buckets (dst>>8)
#define CHE 4096       // edges per chunk

typedef float f32x4 __attribute__((ext_vector_type(4)));
typedef short s16x8 __attribute__((ext_vector_type(8)));

__device__ __forceinline__ ushort f2b(float f) {
    uint x = __float_as_uint(f);
    x += ((x >> 16) & 1u) + 0x7fffu;   // round-to-nearest-even
    return (ushort)(x >> 16);
}

// ---------------- P1: cvt_x | prep_w | per-chunk histograms of dst>>8 ----------------

#define CVT_BLOCKS 12500   // 3.2M float4
#define PREP_BLOCKS 465
#define HIST_BLOCKS NBK

__global__ __launch_bounds__(256) void front(
    const float* __restrict__ xa, const float* __restrict__ xp,
    ushort* __restrict__ oa, ushort* __restrict__ op,
    const float* __restrict__ Wl, const float* __restrict__ Wr,
    const float* __restrict__ linW, const float* __restrict__ bl,
    ushort* __restrict__ wt, float* __restrict__ bsum_p,
    const int* __restrict__ dw, const int* __restrict__ dc, const int* __restrict__ dwb,
    int* __restrict__ Hglob)
{
    __shared__ int hist[NCH];
    int b = blockIdx.x, t = threadIdx.x;
    if (b < CVT_BLOCKS) {
        int i = b * 256 + t;
        const int per = NA * D / 4;
        const float* src; ushort* dst; int li;
        if (i < per) { src = xa; dst = oa; li = i; }
        else { src = xp; dst = op; li = i - per; }
        float4 v = *(const float4*)&src[(size_t)li * 4];
        ushort4 o;
        o.x = f2b(v.x); o.y = f2b(v.y); o.z = f2b(v.z); o.w = f2b(v.w);
        *(ushort4*)&dst[(size_t)li * 4] = o;
    } else if (b < CVT_BLOCKS + PREP_BLOCKS) {
        int b2 = b - CVT_BLOCKS;
        if (b2 < 448) {
            int job = b2 >> 6;
            int idx = (b2 & 63) * 256 + t;
            int n = idx >> 7, k = idx & 127;
            const float* src;
            float add = 0.f;
            switch (job) {
                case 0: src = Wl + 0 * DD; break;
                case 1: src = Wl + 2 * DD; break;
                case 2: src = Wr + 0 * DD; add = Wr[2 * DD + k * D + n]; break;
                case 3: src = Wl + 1 * DD; break;
                case 4: src = Wr + 1 * DD; break;
                case 5: src = Wl + 4 * DD; break;
                default: src = Wr + 4 * DD; break;
            }
            wt[(size_t)job * DD + idx] = f2b(src[k * D + n] + add);
        } else if (b2 < 464) {
            int idx = (b2 - 448) * 256 + t;    // linW^T: n<32, k<128
            int n = idx >> 7, k = idx & 127;
            wt[(size_t)7 * DD + idx] = f2b(linW[k * OUTD + n]);
        } else {
            if (t < D) bsum_p[t] = bl[t] + bl[2 * D + t];
        }
    } else {
        int hb = b - CVT_BLOCKS - PREP_BLOCKS;
        int r = hb / NCH, c = hb % NCH;
        const int* dp = (r == 0) ? dw : ((r == 1) ? dc : dwb);
        for (int i = t; i < NCH; i += 256) hist[i] = 0;
        __syncthreads();
        int base = c * CHE;
#pragma unroll
        for (int i = 0; i < 16; ++i) {
            int e = base + i * 256 + t;
            if (e < NE) atomicAdd(&hist[dp[e] >> 8], 1);
        }
        __syncthreads();
        for (int dg = t; dg < NCH; dg += 256)
            Hglob[(r * NCH + dg) * NCH + c] = hist[dg];
    }
}

// ---------------- P2a: per-bucket exclusive scan over chunks ----------------

__global__ __launch_bounds__(64) void scan_chunks(
    const int* __restrict__ Hglob, int* __restrict__ OFF, int* __restrict__ T)
{
    int gd = blockIdx.x, t = threadIdx.x;
    int carry = 0;
#pragma unroll
    for (int rnd = 0; rnd < 4; ++rnd) {
        int idx = rnd * 64 + t;
        int v = (idx < NCH) ? Hglob[gd * NCH + idx] : 0;
        int x = v;
#pragma unroll
        for (int off = 1; off < 64; off <<= 1) {
            int y = __shfl_up(x, off, 64);
            if (t >= off) x += y;
        }
        if (idx < NCH) OFF[gd * NCH + idx] = carry + x - v;
        carry += __shfl(x, 63, 64);
    }
    if (t == 0) T[gd] = carry;
}

// ---------------- P2b: exclusive scan over 588 bucket totals ----------------

__global__ __launch_bounds__(64) void scan_buckets(
    const int* __restrict__ T, int* __restrict__ B)
{
    int t = threadIdx.x, carry = 0;
#pragma unroll
    for (int rnd = 0; rnd < 10; ++rnd) {
        int idx = rnd * 64 + t;
        int v = (idx < NBK) ? T[idx] : 0;
        int x = v;
#pragma unroll
        for (int off = 1; off < 64; off <<= 1) {
            int y = __shfl_up(x, off, 64);
            if (t >= off) x += y;
        }
        if (idx < NBK) B[idx] = carry + x - v;
        carry += __shfl(x, 63, 64);
    }
}

// ---------------- P3: scatter edges into buckets (LDS ranks, no global atomics) ----------------

__global__ __launch_bounds__(256) void bucket_scatter(
    const int* __restrict__ sw, const int* __restrict__ dw,
    const int* __restrict__ sc_, const int* __restrict__ dc,
    const int* __restrict__ swb, const int* __restrict__ dwb,
    const int* __restrict__ B, const int* __restrict__ OFF,
    uint* __restrict__ bucketed)
{
    __shared__ int lbase[NCH];
    __shared__ int cnt2[NCH];
    int b = blockIdx.x, t = threadIdx.x;
    int r = b / NCH, c = b % NCH;
    const int* sp = (r == 0) ? sw : ((r == 1) ? sc_ : swb);
    const int* dp = (r == 0) ? dw : ((r == 1) ? dc : dwb);
    for (int i = t; i < NCH; i += 256) {
        int gd = r * NCH + i;
        lbase[i] = B[gd] + OFF[gd * NCH + c];
        cnt2[i] = 0;
    }
    __syncthreads();
    int base = c * CHE;
#pragma unroll
    for (int i = 0; i < 16; ++i) {
        int e = base + i * 256 + t;
        if (e < NE) {
            int d = dp[e], s = sp[e];
            int dg = d >> 8;
            int rk = atomicAdd(&cnt2[dg], 1);
            bucketed[lbase[dg] + rk] = ((uint)d << 16) | (uint)s;
        }
    }
}

// ---------------- P4: within-bucket sort by dst low byte -> csr16 + rowptr ----------------

__global__ __launch_bounds__(256) void bucket_sort(
    const uint* __restrict__ bucketed, const int* __restrict__ B,
    const int* __restrict__ T, ushort* __restrict__ csr16,
    int* __restrict__ rowptr)
{
    __shared__ int h[256], bb[256], c3[256];
    int gd = blockIdx.x, t = threadIdx.x;
    int r = gd / NCH, hb = gd % NCH;
    int beg = B[gd], n = T[gd];
    h[t] = 0; c3[t] = 0;
    __syncthreads();
    for (int i = t; i < n; i += 256)
        atomicAdd(&h[(bucketed[beg + i] >> 16) & 255], 1);
    __syncthreads();
    if (t < 64) {
        int carry = 0;
#pragma unroll
        for (int rnd = 0; rnd < 4; ++rnd) {
            int idx = rnd * 64 + t;
            int v = h[idx], x = v;
#pragma unroll
            for (int off = 1; off < 64; off <<= 1) {
                int y = __shfl_up(x, off, 64);
                if (t >= off) x += y;
            }
            bb[idx] = carry + x - v;
            carry += __shfl(x, 63, 64);
        }
    }
    __syncthreads();
    {
        int dst = hb * 256 + t;
        if (dst < 50000) rowptr[r * 50000 + dst] = beg + bb[t];
    }
    for (int i = t; i < n; i += 256) {
        uint rec = bucketed[beg + i];
        int low = (rec >> 16) & 255;
        int rk = atomicAdd(&c3[low], 1);
        csr16[beg + bb[low] + rk] = (ushort)(rec & 0xffffu);
    }
    if (gd == NBK - 1 && t == 0) rowptr[NSEG] = 3 * NE;
}

// ---------------- gather-mean v2: 16 lanes/row, 4 rows per load instr ----------------
// Index prefetch (1 coalesced load per 64 edges) + __shfl broadcast removes the
// dependent index load from the inner latency chain; uint4 loads put 16 rows
// in flight per wave (vs 4 before).

__device__ __forceinline__ void gather_node(
    const ushort* __restrict__ x, const ushort* __restrict__ bk, int n,
    int l, int g, int c, ushort* __restrict__ outp)
{
    float acc[8];
#pragma unroll
    for (int k = 0; k < 8; ++k) acc[k] = 0.f;

    for (int base = 0; base < n; base += 64) {
        int rem = n - base;
        int m = rem > 64 ? 64 : rem;
        int idx = (l < m) ? (int)bk[base + l] : 0;
#pragma unroll 4
        for (int j = 0; j < m; j += 4) {
            int row = __shfl(idx, j + g, 64);
            bool valid = (j + g) < m;
            uint4 u = *(const uint4*)&x[(size_t)row * D + c * 8];
            if (!valid) { u.x = 0; u.y = 0; u.z = 0; u.w = 0; }
            acc[0] += __uint_as_float(u.x << 16);
            acc[1] += __uint_as_float(u.x & 0xffff0000u);
            acc[2] += __uint_as_float(u.y << 16);
            acc[3] += __uint_as_float(u.y & 0xffff0000u);
            acc[4] += __uint_as_float(u.z << 16);
            acc[5] += __uint_as_float(u.z & 0xffff0000u);
            acc[6] += __uint_as_float(u.w << 16);
            acc[7] += __uint_as_float(u.w & 0xffff0000u);
        }
    }
#pragma unroll
    for (int k = 0; k < 8; ++k) {
        acc[k] += __shfl_xor(acc[k], 16, 64);
        acc[k] += __shfl_xor(acc[k], 32, 64);
    }
    if (g == 0) {
        float scl = (n > 0) ? 1.0f / (float)n : 0.f;
        uint4 o;
        o.x = (uint)f2b(acc[0] * scl) | ((uint)f2b(acc[1] * scl) << 16);
        o.y = (uint)f2b(acc[2] * scl) | ((uint)f2b(acc[3] * scl) << 16);
        o.z = (uint)f2b(acc[4] * scl) | ((uint)f2b(acc[5] * scl) << 16);
        o.w = (uint)f2b(acc[6] * scl) | ((uint)f2b(acc[7] * scl) << 16);
        *(uint4*)&outp[c * 8] = o;
    }
}

__global__ __launch_bounds__(256) void gather3(
    const ushort* __restrict__ xa, const ushort* __restrict__ xp,
    const int* __restrict__ rowptr, const ushort* __restrict__ csr16,
    ushort* __restrict__ agg3)
{
    int wid = (blockIdx.x * 256 + threadIdx.x) >> 6;
    if (wid >= NSEG) return;
    const ushort* x = (wid < 50000) ? xa : xp;
    int l = threadIdx.x & 63;
    int beg = __builtin_amdgcn_readfirstlane(rowptr[wid]);
    int end = __builtin_amdgcn_readfirstlane(rowptr[wid + 1]);
    gather_node(x, csr16 + beg, end - beg, l, l >> 4, l & 15,
                agg3 + (size_t)wid * D);
}

__global__ __launch_bounds__(256) void gather_l1(
    const ushort* __restrict__ x, const int* __restrict__ rowptr,
    const ushort* __restrict__ csr16, ushort* __restrict__ out)
{
    int wid = (blockIdx.x * 256 + threadIdx.x) >> 6;
    if (wid >= NA) return;
    int l = threadIdx.x & 63;
    int beg = __builtin_amdgcn_readfirstlane(rowptr[100000 + wid]);
    int end = __builtin_amdgcn_readfirstlane(rowptr[100000 + wid + 1]);
    gather_node(x, csr16 + beg, end - beg, l, l >> 4, l & 15,
                out + (size_t)wid * D);
}

// ---------------- MFMA bf16 GEMM core ----------------

#define LDA 136

__device__ __forceinline__ void gemm_core(
    ushort* As, f32x4 (&acc)[2][4],
    const ushort* __restrict__ A0, const ushort* __restrict__ WT0,
    const ushort* __restrict__ A1, const ushort* __restrict__ WT1,
    const ushort* __restrict__ A2, const ushort* __restrict__ WT2,
    int nseg, int brow, int M)
{
    const int t = threadIdx.x;
    const int w = t >> 6;
    const int l = t & 63;
    const int wr = w >> 1, wc = w & 1;
    const int l15 = l & 15, l4 = l >> 4;

    for (int s = 0; s < nseg; ++s) {
        const ushort* A = (s == 0) ? A0 : ((s == 1) ? A1 : A2);
        const ushort* WT = (s == 0) ? WT0 : ((s == 1) ? WT1 : WT2);

        if (s) __syncthreads();
#pragma unroll
        for (int it = 0; it < 4; ++it) {
            int f = it * 256 + t;
            int row = f >> 4, cc = f & 15;
            int grow = brow + row;
            float4 v = make_float4(0.f, 0.f, 0.f, 0.f);
            if (grow < M) v = *(const float4*)&A[(size_t)grow * D + cc * 8];
            *(float4*)&As[row * LDA + cc * 8] = v;
        }
        s16x8 Bf[4][4];
#pragma unroll
        for (int ni = 0; ni < 4; ++ni)
#pragma unroll
            for (int ks = 0; ks < 4; ++ks)
                Bf[ni][ks] = *(const s16x8*)&WT[(size_t)(wc * 64 + ni * 16 + l15) * D + ks * 32 + l4 * 8];
        __syncthreads();

#pragma unroll
        for (int ks = 0; ks < 4; ++ks) {
            s16x8 af[2];
#pragma unroll
            for (int mi = 0; mi < 2; ++mi)
                af[mi] = *(const s16x8*)&As[(wr * 32 + mi * 16 + l15) * LDA + ks * 32 + l4 * 8];
#pragma unroll
            for (int mi = 0; mi < 2; ++mi)
#pragma unroll
                for (int ni = 0; ni < 4; ++ni)
                    acc[mi][ni] = __builtin_amdgcn_mfma_f32_16x16x32_bf16(
                        af[mi], Bf[ni][ks], acc[mi][ni], 0, 0, 0);
        }
    }
}

// both layer-0 GEMMs in one dispatch
__global__ __launch_bounds__(256) void gemm_pair(
    const ushort* __restrict__ agg3, const ushort* __restrict__ xb_p,
    const ushort* __restrict__ xb_a, const ushort* __restrict__ wt,
    const float* __restrict__ bsum_p, const float* __restrict__ bl,
    ushort* __restrict__ p1b, ushort* __restrict__ a1b)
{
    __shared__ ushort As[64 * LDA];
    const int t = threadIdx.x;
    const int w = t >> 6;
    const int l = t & 63;
    const int wr = w >> 1, wc = w & 1;
    const int l15 = l & 15, l4 = l >> 4;

    f32x4 acc[2][4];
#pragma unroll
    for (int i = 0; i < 2; ++i)
#pragma unroll
        for (int j = 0; j < 4; ++j) acc[i][j] = (f32x4){0.f, 0.f, 0.f, 0.f};

    bool isP = blockIdx.x < 782;
    int bIdx = isP ? blockIdx.x : blockIdx.x - 782;
    int brow = bIdx * 64;
    const float* bias;
    ushort* C;
    if (isP) {
        gemm_core(As, acc, agg3, wt + 0 * DD, agg3 + (size_t)50000 * D, wt + 1 * DD,
                  xb_p, wt + 2 * DD, 3, brow, NP);
        bias = bsum_p; C = p1b;
    } else {
        gemm_core(As, acc, agg3 + (size_t)100000 * D, wt + 3 * DD, xb_a, wt + 4 * DD,
                  nullptr, nullptr, 2, brow, NA);
        bias = bl + 1 * D; C = a1b;
    }

#pragma unroll
    for (int mi = 0; mi < 2; ++mi) {
#pragma unroll
        for (int ni = 0; ni < 4; ++ni) {
            int col = wc * 64 + ni * 16 + l15;
            float bb = bias[col];
#pragma unroll
            for (int r = 0; r < 4; ++r) {
                int grow = brow + wr * 32 + mi * 16 + l4 * 4 + r;
                if (grow >= 50000) continue;
                float v = acc[mi][ni][r] + bb;
                v = v > 0.f ? v : 0.01f * v;
                C[(size_t)grow * D + col] = f2b(v);
            }
        }
    }
}

// layer-1 author GEMM with fused final projection
__global__ __launch_bounds__(256) void gemm_final(
    const ushort* __restrict__ A0, const ushort* __restrict__ WT0,
    const ushort* __restrict__ A1, const ushort* __restrict__ WT1,
    const float* __restrict__ bias,
    const ushort* __restrict__ linWT, const float* __restrict__ linb,
    float* __restrict__ fout, int M)
{
    __shared__ ushort As[64 * LDA];
    const int t = threadIdx.x;
    const int w = t >> 6;
    const int l = t & 63;
    const int wr = w >> 1, wc = w & 1;
    const int l15 = l & 15, l4 = l >> 4;
    const int brow = blockIdx.x * 64;

    f32x4 acc[2][4];
#pragma unroll
    for (int i = 0; i < 2; ++i)
#pragma unroll
        for (int j = 0; j < 4; ++j) acc[i][j] = (f32x4){0.f, 0.f, 0.f, 0.f};

    gemm_core(As, acc, A0, WT0, A1, WT1, nullptr, nullptr, 2, brow, M);

    __syncthreads();
#pragma unroll
    for (int mi = 0; mi < 2; ++mi) {
#pragma unroll
        for (int ni = 0; ni < 4; ++ni) {
            int col = wc * 64 + ni * 16 + l15;
            float bb = bias[col];
#pragma unroll
            for (int r = 0; r < 4; ++r) {
                int row = wr * 32 + mi * 16 + l4 * 4 + r;
                float v = acc[mi][ni][r] + bb;
                v = v > 0.f ? v : 0.01f * v;
                As[row * LDA + col] = f2b(v);
            }
        }
    }
    __syncthreads();
    f32x4 a2c[2];
    a2c[0] = (f32x4){0.f, 0.f, 0.f, 0.f};
    a2c[1] = (f32x4){0.f, 0.f, 0.f, 0.f};
#pragma unroll
    for (int ks = 0; ks < 4; ++ks) {
        s16x8 af = *(const s16x8*)&As[(w * 16 + l15) * LDA + ks * 32 + l4 * 8];
#pragma unroll
        for (int ni = 0; ni < 2; ++ni) {
            s16x8 bf = *(const s16x8*)&linWT[(size_t)(ni * 16 + l15) * D + ks * 32 + l4 * 8];
            a2c[ni] = __builtin_amdgcn_mfma_f32_16x16x32_bf16(af, bf, a2c[ni], 0, 0, 0);
        }
    }
#pragma unroll
    for (int ni = 0; ni < 2; ++ni) {
        int col = ni * 16 + l15;
        float bb = linb[col];
#pragma unroll
        for (int r = 0; r < 4; ++r) {
            int grow = brow + w * 16 + l4 * 4 + r;
            if (grow < M) fout[(size_t)grow * OUTD + col] = a2c[ni][r] + bb;
        }
    }
}

// ---------------- launch ----------------

extern "C" void kernel_launch(void* const* d_in, const int* in_sizes, int n_in,
                              void* d_out, int out_size, void* d_ws, size_t ws_size,
                              hipStream_t stream)
{
    const float* x_author = (const float*)d_in[0];
    const float* x_paper  = (const float*)d_in[1];
    const int*   e_w      = (const int*)d_in[2];   // author -> paper  (r=0)
    const int*   e_wb     = (const int*)d_in[3];   // paper  -> author (r=2)
    const int*   e_c      = (const int*)d_in[4];   // paper  -> paper  (r=1)
    const float* Wl       = (const float*)d_in[5];
    const float* bl       = (const float*)d_in[6];
    const float* Wr       = (const float*)d_in[7];
    const float* linW     = (const float*)d_in[8];
    const float* linb     = (const float*)d_in[9];
    float* out = (float*)d_out;

    // ---- workspace ----
    int* ib = (int*)d_ws;
    int* Hglob  = ib;                       // 588*196 = 115248
    int* OFF    = ib + 115248;              // 115248
    int* T      = ib + 230496;              // 588
    int* B      = ib + 231084;              // 589 (pad region to 231680)
    int* rowptr = ib + 231680;              // 150001 (pad to 381696)
    uint* bucketed = (uint*)(ib + 381696);  // 2400000
    ushort* csr16  = (ushort*)(ib + 2781696); // 2400000 ushort (1.2M ints)
    float* bsum_p  = (float*)(ib + 3981696);  // 128
    ushort* ub = (ushort*)(ib + 3981824);
    ushort* wt   = ub;                      // 8*16384
    ushort* xb_a = ub + 131072;
    ushort* xb_p = xb_a + (size_t)NA * D;
    ushort* agg3 = xb_p + (size_t)NP * D;   // [150000][D]
    ushort* p1b  = agg3 + (size_t)NSEG * D;
    ushort* a1b  = p1b + (size_t)NP * D;
    ushort* g2b  = agg3;   // reuse after gemm_pair consumed agg3

    // P1: cvt | prep | histograms (no global atomics anywhere)
    front<<<CVT_BLOCKS + PREP_BLOCKS + HIST_BLOCKS, 256, 0, stream>>>(
        x_author, x_paper, xb_a, xb_p,
        Wl, Wr, linW, bl, wt, bsum_p,
        e_w + NE, e_c + NE, e_wb + NE, Hglob);

    // P2: scans
    scan_chunks<<<NBK, 64, 0, stream>>>(Hglob, OFF, T);
    scan_buckets<<<1, 64, 0, stream>>>(T, B);

    // P3: scatter into buckets
    bucket_scatter<<<NBK, 256, 0, stream>>>(
        e_w, e_w + NE, e_c, e_c + NE, e_wb, e_wb + NE, B, OFF, bucketed);

    // P4: within-bucket sort -> csr16 + rowptr
    bucket_sort<<<NBK, 256, 0, stream>>>(bucketed, B, T, csr16, rowptr);

    // layer-0 gathers (150000 waves)
    gather3<<<NSEG * 64 / 256, 256, 0, stream>>>(xb_a, xb_p, rowptr, csr16, agg3);

    // both layer-0 GEMMs
    gemm_pair<<<1564, 256, 0, stream>>>(agg3, xb_p, xb_a, wt, bsum_p, bl, p1b, a1b);

    // layer-1 gather of p1 over written_by
    gather_l1<<<NA * 64 / 256, 256, 0, stream>>>(p1b, rowptr, csr16, g2b);

    // a2 = lrelu(g2@Wl11 + a1@Wr11 + bl11); out = a2@linW + linb (fused)
    gemm_final<<<(NA + 63) / 64, 256, 0, stream>>>(
        g2b, wt + 5 * DD, a1b, wt + 6 * DD, bl + 4 * D, wt + 7 * DD, linb, out, NA);
}

// Round 8
// 247.417 us; speedup vs baseline: 1.7164x; 1.0044x over previous
//
#include <hip/hip_runtime.h>

#define NA 50000
#define NP 50000
#define NE 800000
#define D 128
#define OUTD 32
#define NSEG 150000
#define DD (D * D)
#define NCH 196        // chunks per relation (4096 edges each)
#define NBK 588        // 3 relations x 196 buckets (dst>>8)
#define CHE 4096       // edges per chunk
#define ZROW 50000     // index of the all-zeros pad row

typedef float f32x4 __attribute__((ext_vector_type(4)));
typedef short s16x8 __attribute__((ext_vector_type(8)));

__device__ __forceinline__ ushort f2b(float f) {
    uint x = __float_as_uint(f);
    x += ((x >> 16) & 1u) + 0x7fffu;   // round-to-nearest-even
    return (ushort)(x >> 16);
}

// ---------------- P1: cvt_x | prep_w | zero-pad rows | per-chunk histograms ----------------

#define CVT_BLOCKS 12500   // 3.2M float4
#define PREP_BLOCKS 466    // 465 weight-prep + 1 zero-pad-rows
#define HIST_BLOCKS NBK

__global__ __launch_bounds__(256) void front(
    const float* __restrict__ xa, const float* __restrict__ xp,
    ushort* __restrict__ oa, ushort* __restrict__ op,
    const float* __restrict__ Wl, const float* __restrict__ Wr,
    const float* __restrict__ linW, const float* __restrict__ bl,
    ushort* __restrict__ wt, float* __restrict__ bsum_p,
    ushort* __restrict__ p1b,
    const int* __restrict__ dw, const int* __restrict__ dc, const int* __restrict__ dwb,
    int* __restrict__ Hglob)
{
    __shared__ int hist[NCH];
    int b = blockIdx.x, t = threadIdx.x;
    if (b < CVT_BLOCKS) {
        int i = b * 256 + t;
        const int per = NA * D / 4;
        const float* src; ushort* dst; int li;
        if (i < per) { src = xa; dst = oa; li = i; }
        else { src = xp; dst = op; li = i - per; }
        float4 v = *(const float4*)&src[(size_t)li * 4];
        ushort4 o;
        o.x = f2b(v.x); o.y = f2b(v.y); o.z = f2b(v.z); o.w = f2b(v.w);
        *(ushort4*)&dst[(size_t)li * 4] = o;
    } else if (b < CVT_BLOCKS + PREP_BLOCKS) {
        int b2 = b - CVT_BLOCKS;
        if (b2 < 448) {
            int job = b2 >> 6;
            int idx = (b2 & 63) * 256 + t;
            int n = idx >> 7, k = idx & 127;
            const float* src;
            float add = 0.f;
            switch (job) {
                case 0: src = Wl + 0 * DD; break;
                case 1: src = Wl + 2 * DD; break;
                case 2: src = Wr + 0 * DD; add = Wr[2 * DD + k * D + n]; break;
                case 3: src = Wl + 1 * DD; break;
                case 4: src = Wr + 1 * DD; break;
                case 5: src = Wl + 4 * DD; break;
                default: src = Wr + 4 * DD; break;
            }
            wt[(size_t)job * DD + idx] = f2b(src[k * D + n] + add);
        } else if (b2 < 464) {
            int idx = (b2 - 448) * 256 + t;    // linW^T: n<32, k<128
            int n = idx >> 7, k = idx & 127;
            wt[(size_t)7 * DD + idx] = f2b(linW[k * OUTD + n]);
        } else if (b2 == 464) {
            if (t < D) bsum_p[t] = bl[t] + bl[2 * D + t];
        } else {
            // zero the pad rows (index ZROW) of oa, op, p1b
            if (t < 64)       ((uint*)(oa + (size_t)ZROW * D))[t] = 0;
            else if (t < 128) ((uint*)(op + (size_t)ZROW * D))[t - 64] = 0;
            else if (t < 192) ((uint*)(p1b + (size_t)ZROW * D))[t - 128] = 0;
        }
    } else {
        int hb = b - CVT_BLOCKS - PREP_BLOCKS;
        int r = hb / NCH, c = hb % NCH;
        const int* dp = (r == 0) ? dw : ((r == 1) ? dc : dwb);
        for (int i = t; i < NCH; i += 256) hist[i] = 0;
        __syncthreads();
        int base = c * CHE;
#pragma unroll
        for (int i = 0; i < 16; ++i) {
            int e = base + i * 256 + t;
            if (e < NE) atomicAdd(&hist[dp[e] >> 8], 1);
        }
        __syncthreads();
        for (int dg = t; dg < NCH; dg += 256)
            Hglob[(r * NCH + dg) * NCH + c] = hist[dg];
    }
}

// ---------------- P2a: per-bucket exclusive scan over chunks ----------------

__global__ __launch_bounds__(64) void scan_chunks(
    const int* __restrict__ Hglob, int* __restrict__ OFF, int* __restrict__ T)
{
    int gd = blockIdx.x, t = threadIdx.x;
    int carry = 0;
#pragma unroll
    for (int rnd = 0; rnd < 4; ++rnd) {
        int idx = rnd * 64 + t;
        int v = (idx < NCH) ? Hglob[gd * NCH + idx] : 0;
        int x = v;
#pragma unroll
        for (int off = 1; off < 64; off <<= 1) {
            int y = __shfl_up(x, off, 64);
            if (t >= off) x += y;
        }
        if (idx < NCH) OFF[gd * NCH + idx] = carry + x - v;
        carry += __shfl(x, 63, 64);
    }
    if (t == 0) T[gd] = carry;
}

// ---------------- P2b: exclusive scan over 588 bucket totals ----------------

__global__ __launch_bounds__(64) void scan_buckets(
    const int* __restrict__ T, int* __restrict__ B)
{
    int t = threadIdx.x, carry = 0;
#pragma unroll
    for (int rnd = 0; rnd < 10; ++rnd) {
        int idx = rnd * 64 + t;
        int v = (idx < NBK) ? T[idx] : 0;
        int x = v;
#pragma unroll
        for (int off = 1; off < 64; off <<= 1) {
            int y = __shfl_up(x, off, 64);
            if (t >= off) x += y;
        }
        if (idx < NBK) B[idx] = carry + x - v;
        carry += __shfl(x, 63, 64);
    }
}

// ---------------- P3: scatter edges into buckets (LDS ranks, no global atomics) ----------------

__global__ __launch_bounds__(256) void bucket_scatter(
    const int* __restrict__ sw, const int* __restrict__ dw,
    const int* __restrict__ sc_, const int* __restrict__ dc,
    const int* __restrict__ swb, const int* __restrict__ dwb,
    const int* __restrict__ B, const int* __restrict__ OFF,
    uint* __restrict__ bucketed)
{
    __shared__ int lbase[NCH];
    __shared__ int cnt2[NCH];
    int b = blockIdx.x, t = threadIdx.x;
    int r = b / NCH, c = b % NCH;
    const int* sp = (r == 0) ? sw : ((r == 1) ? sc_ : swb);
    const int* dp = (r == 0) ? dw : ((r == 1) ? dc : dwb);
    for (int i = t; i < NCH; i += 256) {
        int gd = r * NCH + i;
        lbase[i] = B[gd] + OFF[gd * NCH + c];
        cnt2[i] = 0;
    }
    __syncthreads();
    int base = c * CHE;
#pragma unroll
    for (int i = 0; i < 16; ++i) {
        int e = base + i * 256 + t;
        if (e < NE) {
            int d = dp[e], s = sp[e];
            int dg = d >> 8;
            int rk = atomicAdd(&cnt2[dg], 1);
            bucketed[lbase[dg] + rk] = ((uint)d << 16) | (uint)s;
        }
    }
}

// ---------------- P4: within-bucket sort by dst low byte -> csr16 + rowptr ----------------

__global__ __launch_bounds__(256) void bucket_sort(
    const uint* __restrict__ bucketed, const int* __restrict__ B,
    const int* __restrict__ T, ushort* __restrict__ csr16,
    int* __restrict__ rowptr)
{
    __shared__ int h[256], bb[256], c3[256];
    int gd = blockIdx.x, t = threadIdx.x;
    int r = gd / NCH, hb = gd % NCH;
    int beg = B[gd], n = T[gd];
    h[t] = 0; c3[t] = 0;
    __syncthreads();
    for (int i = t; i < n; i += 256)
        atomicAdd(&h[(bucketed[beg + i] >> 16) & 255], 1);
    __syncthreads();
    if (t < 64) {
        int carry = 0;
#pragma unroll
        for (int rnd = 0; rnd < 4; ++rnd) {
            int idx = rnd * 64 + t;
            int v = h[idx], x = v;
#pragma unroll
            for (int off = 1; off < 64; off <<= 1) {
                int y = __shfl_up(x, off, 64);
                if (t >= off) x += y;
            }
            bb[idx] = carry + x - v;
            carry += __shfl(x, 63, 64);
        }
    }
    __syncthreads();
    {
        int dst = hb * 256 + t;
        if (dst < 50000) rowptr[r * 50000 + dst] = beg + bb[t];
    }
    for (int i = t; i < n; i += 256) {
        uint rec = bucketed[beg + i];
        int low = (rec >> 16) & 255;
        int rk = atomicAdd(&c3[low], 1);
        csr16[beg + bb[low] + rk] = (ushort)(rec & 0xffffu);
    }
    if (gd == NBK - 1 && t == 0) rowptr[NSEG] = 3 * NE;
}

// ---------------- gather-mean v3: zero-row pad + v_dot2_f32_bf16 accumulate ----------------
// 16 lanes per row, 4 rows in flight per wave instruction. Pad lanes point at
// the all-zeros row ZROW -> no per-load masking. Each uint (2 bf16) folds into
// two f32 accumulators via v_dot2_f32_bf16 with masks (1,0)/(0,1) -- numerics
// identical to unpack+add (bf16*1.0 exact, f32 accumulate).

#define DOT2(a, u, m) asm("v_dot2_f32_bf16 %0, %1, %2, %0" : "+v"(a) : "v"(u), "v"(m))

__device__ __forceinline__ void gather_node(
    const ushort* __restrict__ x, const ushort* __restrict__ bk, int n,
    int l, int g, int c, ushort* __restrict__ outp)
{
    float acc[8];
#pragma unroll
    for (int k = 0; k < 8; ++k) acc[k] = 0.f;
    const uint mlo = 0x00003f80u;   // bf16 (1.0, 0)
    const uint mhi = 0x3f800000u;   // bf16 (0, 1.0)
    const uint cb = (uint)c * 16;   // byte offset within row

    for (int base = 0; base < n; base += 64) {
        int rem = n - base;
        int m = rem > 64 ? 64 : rem;
        int idx = (l < m) ? (int)bk[base + l] : ZROW;
        int mceil = (m + 3) & ~3;
#pragma unroll 2
        for (int j = 0; j < mceil; j += 4) {
            int row = __shfl(idx, j + g, 64);
            uint4 u = *(const uint4*)((const char*)x + (((uint)row << 8) + cb));
            DOT2(acc[0], u.x, mlo); DOT2(acc[1], u.x, mhi);
            DOT2(acc[2], u.y, mlo); DOT2(acc[3], u.y, mhi);
            DOT2(acc[4], u.z, mlo); DOT2(acc[5], u.z, mhi);
            DOT2(acc[6], u.w, mlo); DOT2(acc[7], u.w, mhi);
        }
    }
#pragma unroll
    for (int k = 0; k < 8; ++k) {
        acc[k] += __shfl_xor(acc[k], 16, 64);
        acc[k] += __shfl_xor(acc[k], 32, 64);
    }
    if (g == 0) {
        float scl = (n > 0) ? 1.0f / (float)n : 0.f;
        uint4 o;
        o.x = (uint)f2b(acc[0] * scl) | ((uint)f2b(acc[1] * scl) << 16);
        o.y = (uint)f2b(acc[2] * scl) | ((uint)f2b(acc[3] * scl) << 16);
        o.z = (uint)f2b(acc[4] * scl) | ((uint)f2b(acc[5] * scl) << 16);
        o.w = (uint)f2b(acc[6] * scl) | ((uint)f2b(acc[7] * scl) << 16);
        *(uint4*)&outp[c * 8] = o;
    }
}

__global__ __launch_bounds__(256) void gather3(
    const ushort* __restrict__ xa, const ushort* __restrict__ xp,
    const int* __restrict__ rowptr, const ushort* __restrict__ csr16,
    ushort* __restrict__ agg3)
{
    int wid = (blockIdx.x * 256 + threadIdx.x) >> 6;
    if (wid >= NSEG) return;
    const ushort* x = (wid < 50000) ? xa : xp;
    int l = threadIdx.x & 63;
    int beg = __builtin_amdgcn_readfirstlane(rowptr[wid]);
    int end = __builtin_amdgcn_readfirstlane(rowptr[wid + 1]);
    gather_node(x, csr16 + beg, end - beg, l, l >> 4, l & 15,
                agg3 + (size_t)wid * D);
}

__global__ __launch_bounds__(256) void gather_l1(
    const ushort* __restrict__ x, const int* __restrict__ rowptr,
    const ushort* __restrict__ csr16, ushort* __restrict__ out)
{
    int wid = (blockIdx.x * 256 + threadIdx.x) >> 6;
    if (wid >= NA) return;
    int l = threadIdx.x & 63;
    int beg = __builtin_amdgcn_readfirstlane(rowptr[100000 + wid]);
    int end = __builtin_amdgcn_readfirstlane(rowptr[100000 + wid + 1]);
    gather_node(x, csr16 + beg, end - beg, l, l >> 4, l & 15,
                out + (size_t)wid * D);
}

// ---------------- MFMA bf16 GEMM core ----------------

#define LDA 136

__device__ __forceinline__ void gemm_core(
    ushort* As, f32x4 (&acc)[2][4],
    const ushort* __restrict__ A0, const ushort* __restrict__ WT0,
    const ushort* __restrict__ A1, const ushort* __restrict__ WT1,
    const ushort* __restrict__ A2, const ushort* __restrict__ WT2,
    int nseg, int brow, int M)
{
    const int t = threadIdx.x;
    const int w = t >> 6;
    const int l = t & 63;
    const int wr = w >> 1, wc = w & 1;
    const int l15 = l & 15, l4 = l >> 4;

    for (int s = 0; s < nseg; ++s) {
        const ushort* A = (s == 0) ? A0 : ((s == 1) ? A1 : A2);
        const ushort* WT = (s == 0) ? WT0 : ((s == 1) ? WT1 : WT2);

        if (s) __syncthreads();
#pragma unroll
        for (int it = 0; it < 4; ++it) {
            int f = it * 256 + t;
            int row = f >> 4, cc = f & 15;
            int grow = brow + row;
            float4 v = make_float4(0.f, 0.f, 0.f, 0.f);
            if (grow < M) v = *(const float4*)&A[(size_t)grow * D + cc * 8];
            *(float4*)&As[row * LDA + cc * 8] = v;
        }
        s16x8 Bf[4][4];
#pragma unroll
        for (int ni = 0; ni < 4; ++ni)
#pragma unroll
            for (int ks = 0; ks < 4; ++ks)
                Bf[ni][ks] = *(const s16x8*)&WT[(size_t)(wc * 64 + ni * 16 + l15) * D + ks * 32 + l4 * 8];
        __syncthreads();

#pragma unroll
        for (int ks = 0; ks < 4; ++ks) {
            s16x8 af[2];
#pragma unroll
            for (int mi = 0; mi < 2; ++mi)
                af[mi] = *(const s16x8*)&As[(wr * 32 + mi * 16 + l15) * LDA + ks * 32 + l4 * 8];
#pragma unroll
            for (int mi = 0; mi < 2; ++mi)
#pragma unroll
                for (int ni = 0; ni < 4; ++ni)
                    acc[mi][ni] = __builtin_amdgcn_mfma_f32_16x16x32_bf16(
                        af[mi], Bf[ni][ks], acc[mi][ni], 0, 0, 0);
        }
    }
}

// both layer-0 GEMMs in one dispatch
__global__ __launch_bounds__(256) void gemm_pair(
    const ushort* __restrict__ agg3, const ushort* __restrict__ xb_p,
    const ushort* __restrict__ xb_a, const ushort* __restrict__ wt,
    const float* __restrict__ bsum_p, const float* __restrict__ bl,
    ushort* __restrict__ p1b, ushort* __restrict__ a1b)
{
    __shared__ ushort As[64 * LDA];
    const int t = threadIdx.x;
    const int w = t >> 6;
    const int l = t & 63;
    const int wr = w >> 1, wc = w & 1;
    const int l15 = l & 15, l4 = l >> 4;

    f32x4 acc[2][4];
#pragma unroll
    for (int i = 0; i < 2; ++i)
#pragma unroll
        for (int j = 0; j < 4; ++j) acc[i][j] = (f32x4){0.f, 0.f, 0.f, 0.f};

    bool isP = blockIdx.x < 782;
    int bIdx = isP ? blockIdx.x : blockIdx.x - 782;
    int brow = bIdx * 64;
    const float* bias;
    ushort* C;
    if (isP) {
        gemm_core(As, acc, agg3, wt + 0 * DD, agg3 + (size_t)50000 * D, wt + 1 * DD,
                  xb_p, wt + 2 * DD, 3, brow, NP);
        bias = bsum_p; C = p1b;
    } else {
        gemm_core(As, acc, agg3 + (size_t)100000 * D, wt + 3 * DD, xb_a, wt + 4 * DD,
                  nullptr, nullptr, 2, brow, NA);
        bias = bl + 1 * D; C = a1b;
    }

#pragma unroll
    for (int mi = 0; mi < 2; ++mi) {
#pragma unroll
        for (int ni = 0; ni < 4; ++ni) {
            int col = wc * 64 + ni * 16 + l15;
            float bb = bias[col];
#pragma unroll
            for (int r = 0; r < 4; ++r) {
                int grow = brow + wr * 32 + mi * 16 + l4 * 4 + r;
                if (grow >= 50000) continue;
                float v = acc[mi][ni][r] + bb;
                v = v > 0.f ? v : 0.01f * v;
                C[(size_t)grow * D + col] = f2b(v);
            }
        }
    }
}

// layer-1 author GEMM with fused final projection
__global__ __launch_bounds__(256) void gemm_final(
    const ushort* __restrict__ A0, const ushort* __restrict__ WT0,
    const ushort* __restrict__ A1, const ushort* __restrict__ WT1,
    const float* __restrict__ bias,
    const ushort* __restrict__ linWT, const float* __restrict__ linb,
    float* __restrict__ fout, int M)
{
    __shared__ ushort As[64 * LDA];
    const int t = threadIdx.x;
    const int w = t >> 6;
    const int l = t & 63;
    const int wr = w >> 1, wc = w & 1;
    const int l15 = l & 15, l4 = l >> 4;
    const int brow = blockIdx.x * 64;

    f32x4 acc[2][4];
#pragma unroll
    for (int i = 0; i < 2; ++i)
#pragma unroll
        for (int j = 0; j < 4; ++j) acc[i][j] = (f32x4){0.f, 0.f, 0.f, 0.f};

    gemm_core(As, acc, A0, WT0, A1, WT1, nullptr, nullptr, 2, brow, M);

    __syncthreads();
#pragma unroll
    for (int mi = 0; mi < 2; ++mi) {
#pragma unroll
        for (int ni = 0; ni < 4; ++ni) {
            int col = wc * 64 + ni * 16 + l15;
            float bb = bias[col];
#pragma unroll
            for (int r = 0; r < 4; ++r) {
                int row = wr * 32 + mi * 16 + l4 * 4 + r;
                float v = acc[mi][ni][r] + bb;
                v = v > 0.f ? v : 0.01f * v;
                As[row * LDA + col] = f2b(v);
            }
        }
    }
    __syncthreads();
    f32x4 a2c[2];
    a2c[0] = (f32x4){0.f, 0.f, 0.f, 0.f};
    a2c[1] = (f32x4){0.f, 0.f, 0.f, 0.f};
#pragma unroll
    for (int ks = 0; ks < 4; ++ks) {
        s16x8 af = *(const s16x8*)&As[(w * 16 + l15) * LDA + ks * 32 + l4 * 8];
#pragma unroll
        for (int ni = 0; ni < 2; ++ni) {
            s16x8 bf = *(const s16x8*)&linWT[(size_t)(ni * 16 + l15) * D + ks * 32 + l4 * 8];
            a2c[ni] = __builtin_amdgcn_mfma_f32_16x16x32_bf16(af, bf, a2c[ni], 0, 0, 0);
        }
    }
#pragma unroll
    for (int ni = 0; ni < 2; ++ni) {
        int col = ni * 16 + l15;
        float bb = linb[col];
#pragma unroll
        for (int r = 0; r < 4; ++r) {
            int grow = brow + w * 16 + l4 * 4 + r;
            if (grow < M) fout[(size_t)grow * OUTD + col] = a2c[ni][r] + bb;
        }
    }
}

// ---------------- launch ----------------

extern "C" void kernel_launch(void* const* d_in, const int* in_sizes, int n_in,
                              void* d_out, int out_size, void* d_ws, size_t ws_size,
                              hipStream_t stream)
{
    const float* x_author = (const float*)d_in[0];
    const float* x_paper  = (const float*)d_in[1];
    const int*   e_w      = (const int*)d_in[2];   // author -> paper  (r=0)
    const int*   e_wb     = (const int*)d_in[3];   // paper  -> author (r=2)
    const int*   e_c      = (const int*)d_in[4];   // paper  -> paper  (r=1)
    const float* Wl       = (const float*)d_in[5];
    const float* bl       = (const float*)d_in[6];
    const float* Wr       = (const float*)d_in[7];
    const float* linW     = (const float*)d_in[8];
    const float* linb     = (const float*)d_in[9];
    float* out = (float*)d_out;

    // ---- workspace ----
    int* ib = (int*)d_ws;
    int* Hglob  = ib;                       // 588*196 = 115248
    int* OFF    = ib + 115248;              // 115248
    int* T      = ib + 230496;              // 588
    int* B      = ib + 231084;              // 589 (pad region to 231680)
    int* rowptr = ib + 231680;              // 150001 (pad to 381696)
    uint* bucketed = (uint*)(ib + 381696);  // 2400000
    ushort* csr16  = (ushort*)(ib + 2781696); // 2400000 ushort (1.2M ints)
    float* bsum_p  = (float*)(ib + 3981696);  // 128
    ushort* ub = (ushort*)(ib + 3981824);
    const size_t R1 = 50001 * (size_t)D;    // padded row count (zero row at ZROW)
    ushort* wt   = ub;                      // 8*16384
    ushort* xb_a = ub + 131072;             // [50001][D]
    ushort* xb_p = xb_a + R1;               // [50001][D]
    ushort* agg3 = xb_p + R1;               // [150000][D]
    ushort* p1b  = agg3 + (size_t)NSEG * D; // [50001][D]
    ushort* a1b  = p1b + R1;                // [50000][D]
    ushort* g2b  = agg3;   // reuse after gemm_pair consumed agg3

    // P1: cvt | prep | pad rows | histograms (no global atomics anywhere)
    front<<<CVT_BLOCKS + PREP_BLOCKS + HIST_BLOCKS, 256, 0, stream>>>(
        x_author, x_paper, xb_a, xb_p,
        Wl, Wr, linW, bl, wt, bsum_p, p1b,
        e_w + NE, e_c + NE, e_wb + NE, Hglob);

    // P2: scans
    scan_chunks<<<NBK, 64, 0, stream>>>(Hglob, OFF, T);
    scan_buckets<<<1, 64, 0, stream>>>(T, B);

    // P3: scatter into buckets
    bucket_scatter<<<NBK, 256, 0, stream>>>(
        e_w, e_w + NE, e_c, e_c + NE, e_wb, e_wb + NE, B, OFF, bucketed);

    // P4: within-bucket sort -> csr16 + rowptr
    bucket_sort<<<NBK, 256, 0, stream>>>(bucketed, B, T, csr16, rowptr);

    // layer-0 gathers (150000 waves)
    gather3<<<NSEG * 64 / 256, 256, 0, stream>>>(xb_a, xb_p, rowptr, csr16, agg3);

    // both layer-0 GEMMs
    gemm_pair<<<1564, 256, 0, stream>>>(agg3, xb_p, xb_a, wt, bsum_p, bl, p1b, a1b);

    // layer-1 gather of p1 over written_by
    gather_l1<<<NA * 64 / 256, 256, 0, stream>>>(p1b, rowptr, csr16, g2b);

    // a2 = lrelu(g2@Wl11 + a1@Wr11 + bl11); out = a2@linW + linb (fused)
    gemm_final<<<(NA + 63) / 64, 256, 0, stream>>>(
        g2b, wt + 5 * DD, a1b, wt + 6 * DD, bl + 4 * D, wt + 7 * DD, linb, out, NA);
}